// Round 4
// baseline (3582.478 us; speedup 1.0000x reference)
//
#include <hip/hip_runtime.h>

#define HID 16
#define OUTC 4
#define G 128            // nodes per bucket
#define GSH 7            // log2(G)

__device__ __forceinline__ float relu(float v) { return v > 0.f ? v : 0.f; }

// ---- per-node in-degree histogram ----
__global__ void k_hist(const int* __restrict__ dst, int* __restrict__ hist, int E) {
    for (int i = blockIdx.x * blockDim.x + threadIdx.x; i < E; i += gridDim.x * blockDim.x)
        atomicAdd(hist + dst[i], 1);
}

// ---- per-bucket edge count (sum of degrees) + dinv = rsqrt(deg+1) ----
__global__ void k_bcnt(const int* __restrict__ hist, int* __restrict__ bcnt,
                       float* __restrict__ dinv, int N) {
    __shared__ int s[G];
    int n = blockIdx.x * G + threadIdx.x;
    int v = (n < N) ? hist[n] : 0;
    if (n < N) dinv[n] = rsqrtf((float)v + 1.0f);   // +1 self-loop; deg>0 always
    s[threadIdx.x] = v; __syncthreads();
    for (int off = G / 2; off > 0; off >>= 1) {
        if (threadIdx.x < off) s[threadIdx.x] += s[threadIdx.x + off];
        __syncthreads();
    }
    if (threadIdx.x == 0) bcnt[blockIdx.x] = s[0];
}

// ---- single-block exclusive scan of bucket counts -> bOff, bcur (stride-16 padded) ----
__global__ void k_bscan(const int* __restrict__ bcnt, int* __restrict__ bOff,
                        int* __restrict__ bcur, int nb, int E) {
    __shared__ int s[1024];
    int carry = 0;
    for (int base = 0; base < nb; base += 1024) {
        int idx = base + threadIdx.x;
        int v = (idx < nb) ? bcnt[idx] : 0;
        s[threadIdx.x] = v; __syncthreads();
        for (int off = 1; off < 1024; off <<= 1) {
            int t = (threadIdx.x >= (unsigned)off) ? s[threadIdx.x - off] : 0;
            __syncthreads();
            s[threadIdx.x] += t;
            __syncthreads();
        }
        if (idx < nb) {
            int ex = carry + s[threadIdx.x] - v;
            bOff[idx] = ex;
            bcur[idx * 16] = ex;
        }
        carry += s[1023];
        __syncthreads();
    }
    if (threadIdx.x == 0) bOff[nb] = E;
}

// ---- partition edges into bucket regions as packed records src | dst_local<<18 ----
__global__ void k_part(const int* __restrict__ src, const int* __restrict__ dst,
                       int* __restrict__ bcur, unsigned int* __restrict__ rec, int E) {
    for (int i = blockIdx.x * blockDim.x + threadIdx.x; i < E; i += gridDim.x * blockDim.x) {
        int s = src[i], d = dst[i];
        int b = d >> GSH;
        int p = atomicAdd(bcur + b * 16, 1);
        rec[p] = (unsigned int)s | ((unsigned int)(d & (G - 1)) << 18);
    }
}

// ---- mScaled1[n][c] = x[n] * W1[c] * dinv[n]  (IN_C == 1) ----
__global__ void k_m1(const float* __restrict__ x, const float* __restrict__ W1,
                     const float* __restrict__ dinv, float* __restrict__ m, int N) {
    int t = blockIdx.x * blockDim.x + threadIdx.x;
    if (t < N * HID) {
        int n = t >> 4, c = t & 15;
        m[t] = x[n] * W1[c] * dinv[n];
    }
}

// ---- mScaled2[n][co] = (sum_ci h[n][ci] * W2[ci][co]) * dinv[n] ----
__global__ void k_m2(const float* __restrict__ h, const float* __restrict__ W2,
                     const float* __restrict__ dinv, float* __restrict__ m, int N) {
    __shared__ float w[HID * HID];
    if (threadIdx.x < HID * HID) w[threadIdx.x] = W2[threadIdx.x];
    __syncthreads();
    int t = blockIdx.x * blockDim.x + threadIdx.x;
    if (t < N * HID) {
        int n = t >> 4, co = t & 15;
        const float* hr = h + n * HID;
        float acc = 0.f;
#pragma unroll
        for (int ci = 0; ci < HID; ++ci) acc += hr[ci] * w[ci * HID + co];
        m[t] = acc * dinv[n];
    }
}

// ---- bucket-local aggregation, layer 1: h = relu((agg + mS[n]) * dinv[n] + b) ----
// one block per bucket; 4 lanes per record (channel-quads); LDS f32 accumulate.
__global__ void k_agg1(const int* __restrict__ bOff, const unsigned int* __restrict__ rec,
                       const float* __restrict__ dinv, const float4* __restrict__ mS4,
                       const float4* __restrict__ b4, float4* __restrict__ h4, int N) {
    __shared__ float agg[G * 17];
    int b = blockIdx.x;
    int base = b * G;
    for (int i = threadIdx.x; i < G * 17; i += 256) agg[i] = 0.f;
    __syncthreads();
    int beg = bOff[b], end = bOff[b + 1];
    int q = threadIdx.x & 3;
    for (int i = beg + (threadIdx.x >> 2); i < end; i += 64) {
        unsigned int r = rec[i];
        int s = r & 0x3FFFF;
        int dl = r >> 18;
        float4 mv = mS4[s * 4 + q];
        float* a = agg + dl * 17 + q * 4;
        atomicAdd(a + 0, mv.x); atomicAdd(a + 1, mv.y);
        atomicAdd(a + 2, mv.z); atomicAdd(a + 3, mv.w);
    }
    __syncthreads();
    for (int v = threadIdx.x; v < G * 4; v += 256) {
        int nl = v >> 2, qq = v & 3;
        int n = base + nl;
        if (n >= N) break;
        float dn = dinv[n];
        float4 ms = mS4[n * 4 + qq];
        float4 bb = b4[qq];
        const float* a = agg + nl * 17 + qq * 4;
        float4 hv;
        hv.x = relu((a[0] + ms.x) * dn + bb.x);
        hv.y = relu((a[1] + ms.y) * dn + bb.y);
        hv.z = relu((a[2] + ms.z) * dn + bb.z);
        hv.w = relu((a[3] + ms.w) * dn + bb.w);
        h4[n * 4 + qq] = hv;
    }
}

// ---- layer 2 aggregation fused with readout: out = relu(h2) @ Wl + bl ----
__global__ void k_agg2(const int* __restrict__ bOff, const unsigned int* __restrict__ rec,
                       const float* __restrict__ dinv, const float4* __restrict__ mS4,
                       const float4* __restrict__ b4, const float* __restrict__ Wl,
                       const float* __restrict__ bl, float4* __restrict__ out4, int N) {
    __shared__ float agg[G * 17];
    __shared__ float wl[HID * OUTC];
    __shared__ float blv[OUTC];
    if (threadIdx.x < HID * OUTC) wl[threadIdx.x] = Wl[threadIdx.x];
    if (threadIdx.x < OUTC) blv[threadIdx.x] = bl[threadIdx.x];
    int b = blockIdx.x;
    int base = b * G;
    for (int i = threadIdx.x; i < G * 17; i += 256) agg[i] = 0.f;
    __syncthreads();
    int beg = bOff[b], end = bOff[b + 1];
    int q = threadIdx.x & 3;
    for (int i = beg + (threadIdx.x >> 2); i < end; i += 64) {
        unsigned int r = rec[i];
        int s = r & 0x3FFFF;
        int dl = r >> 18;
        float4 mv = mS4[s * 4 + q];
        float* a = agg + dl * 17 + q * 4;
        atomicAdd(a + 0, mv.x); atomicAdd(a + 1, mv.y);
        atomicAdd(a + 2, mv.z); atomicAdd(a + 3, mv.w);
    }
    __syncthreads();
    // h2 (relu'd) written back into agg in place
    for (int v = threadIdx.x; v < G * 4; v += 256) {
        int nl = v >> 2, qq = v & 3;
        int n = base + nl;
        if (n >= N) break;
        float dn = dinv[n];
        float4 ms = mS4[n * 4 + qq];
        float4 bb = b4[qq];
        float* a = agg + nl * 17 + qq * 4;
        a[0] = relu((a[0] + ms.x) * dn + bb.x);
        a[1] = relu((a[1] + ms.y) * dn + bb.y);
        a[2] = relu((a[2] + ms.z) * dn + bb.z);
        a[3] = relu((a[3] + ms.w) * dn + bb.w);
    }
    __syncthreads();
    for (int nl = threadIdx.x; nl < G; nl += 256) {
        int n = base + nl;
        if (n >= N) break;
        float o0 = blv[0], o1 = blv[1], o2 = blv[2], o3 = blv[3];
        const float* hr = agg + nl * 17;
#pragma unroll
        for (int c = 0; c < HID; ++c) {
            float h = hr[c];
            o0 += h * wl[c * 4 + 0];
            o1 += h * wl[c * 4 + 1];
            o2 += h * wl[c * 4 + 2];
            o3 += h * wl[c * 4 + 3];
        }
        out4[n] = make_float4(o0, o1, o2, o3);
    }
}

// ---------- launch ----------
static inline size_t alignup(size_t v, size_t a) { return (v + a - 1) & ~(a - 1); }

extern "C" void kernel_launch(void* const* d_in, const int* in_sizes, int n_in,
                              void* d_out, int out_size, void* d_ws, size_t ws_size,
                              hipStream_t stream) {
    const float* x  = (const float*)d_in[0];
    const int* ed   = (const int*)d_in[1];     // int inputs delivered as int32
    const float* W1 = (const float*)d_in[2];
    const float* b1 = (const float*)d_in[3];
    const float* W2 = (const float*)d_in[4];
    const float* b2 = (const float*)d_in[5];
    const float* Wl = (const float*)d_in[6];
    const float* bl = (const float*)d_in[7];
    float* out      = (float*)d_out;

    int N = in_sizes[0];
    int E = in_sizes[1] / 2;
    const int* src = ed;
    const int* dst = ed + E;
    int nb = (N + G - 1) / G;                  // buckets of G consecutive nodes

    // workspace layout
    char* w = (char*)d_ws;
    size_t o = 0;
    int* hist          = (int*)(w + o); o = alignup(o + (size_t)N * 4, 16);
    int* bcnt          = (int*)(w + o); o = alignup(o + (size_t)nb * 4, 16);
    int* bOff          = (int*)(w + o); o = alignup(o + ((size_t)nb + 1) * 4, 16);
    int* bcur          = (int*)(w + o); o = alignup(o + (size_t)nb * 16 * 4, 16);  // 64B-strided cursors
    float* dinv        = (float*)(w + o); o = alignup(o + (size_t)N * 4, 16);
    unsigned int* rec  = (unsigned int*)(w + o); o = alignup(o + (size_t)E * 4, 16);
    float* bufA        = (float*)(w + o); o = alignup(o + (size_t)N * HID * 4, 16);
    float* bufB        = (float*)(w + o); o = alignup(o + (size_t)N * HID * 4, 16);
    (void)ws_size;

    int blk = 256;
    int gN16 = (N * HID + blk - 1) / blk;

    // build dinv + bucket-partitioned edge records
    hipMemsetAsync(hist, 0, (size_t)N * 4, stream);
    k_hist<<<4096, blk, 0, stream>>>(dst, hist, E);
    k_bcnt<<<nb, G, 0, stream>>>(hist, bcnt, dinv, N);
    k_bscan<<<1, 1024, 0, stream>>>(bcnt, bOff, bcur, nb, E);
    k_part<<<4096, blk, 0, stream>>>(src, dst, bcur, rec, E);

    // layer 1
    k_m1<<<gN16, blk, 0, stream>>>(x, W1, dinv, bufA, N);
    k_agg1<<<nb, 256, 0, stream>>>(bOff, rec, dinv, (const float4*)bufA,
                                   (const float4*)b1, (float4*)bufB, N);

    // layer 2 + readout
    k_m2<<<gN16, blk, 0, stream>>>(bufB, W2, dinv, bufA, N);
    k_agg2<<<nb, 256, 0, stream>>>(bOff, rec, dinv, (const float4*)bufA,
                                   (const float4*)b2, Wl, bl, (float4*)out, N);
}